// Round 3
// baseline (270.479 us; speedup 1.0000x reference)
//
#include <hip/hip_runtime.h>
#include <hip/hip_bf16.h>

// PinSageConv on MI355X — round 10.
// qgemm v10: async staging. h is pre-converted to bf16 (hB, NEW hcvt kernel)
// with per-row 16B-chunk XOR swizzle (c ^= row&7) baked into the GLOBAL
// layout, so qgemm stages A with 8x global_load_lds(16B) per thread into a
// LINEAR LDS dest (both-sides-or-neither swizzle rule). This removes the
// f32->bf16 VGPR round-trip that capped in-flight loads (~8/wave, 1.1 TB/s,
// 17% HBM) — async staging is vmcnt-limited (64), not VGPR-limited.
// Epilogue reverted to sector-complete uint4 stores via per-wave LDS bounce
// (v9's scattered 4B stores = 4x partial-sector transactions, regressed);
// now dword LDS writes (~4-way conflict) instead of v7's 16-way byte writes.
// B register pipeline back to 2-deep (saves 16 VGPR -> more blocks/CU).
// Workspace: q_fp8[100000][256] @0 | aggF f32 @25.6MB | QwB @46,080,000
//            | WwB @46,211,072 | hB bf16 swizzled @46,473,216 (51.2MB).

#define M_TOTAL 100000
#define N_NODES 20000
#define T_NB    50
#define IN_F    256
#define HID_F   256
#define OUT_F   256
#define KCAT    512

typedef __bf16 bf16x8 __attribute__((ext_vector_type(8)));
typedef float  floatx4 __attribute__((ext_vector_type(4)));
typedef float  v2f     __attribute__((ext_vector_type(2)));

__device__ __forceinline__ unsigned short f2bf(float f) {
    unsigned int u = __float_as_uint(f);
    u += 0x7fffu + ((u >> 16) & 1u);          // RTNE
    return (unsigned short)(u >> 16);
}
__device__ __forceinline__ void gload16(const void* g, void* l) {
    __builtin_amdgcn_global_load_lds(
        (const __attribute__((address_space(1))) unsigned int*)g,
        (__attribute__((address_space(3))) unsigned int*)l, 16, 0, 0);
}
__device__ __forceinline__ bf16x8 cvt_frag(float4 a, float4 b) {
    bf16x8 r;
    r[0] = (__bf16)a.x; r[1] = (__bf16)a.y; r[2] = (__bf16)a.z; r[3] = (__bf16)a.w;
    r[4] = (__bf16)b.x; r[5] = (__bf16)b.y; r[6] = (__bf16)b.z; r[7] = (__bf16)b.w;
    return r;
}

// ---------------------------------------------------------------------------
// Kernel 0: convert Qw (65536 f32) and Ww (131072 f32) to bf16.
// ---------------------------------------------------------------------------
__global__ __launch_bounds__(256)
void wcvt(const float* __restrict__ Qw, const float* __restrict__ Ww,
          unsigned short* __restrict__ QwB, unsigned short* __restrict__ WwB) {
    const int e = (blockIdx.x * 256 + threadIdx.x) * 4;
    float4 v;
    unsigned short* dst;
    if (e < 65536) { v = *(const float4*)(Qw + e);           dst = QwB + e; }
    else           { v = *(const float4*)(Ww + (e - 65536)); dst = WwB + (e - 65536); }
    ushort4 s;
    s.x = f2bf(v.x); s.y = f2bf(v.y); s.z = f2bf(v.z); s.w = f2bf(v.w);
    *(ushort4*)dst = s;
}

// ---------------------------------------------------------------------------
// Kernel 0b (NEW): h f32 -> hB bf16, 16B chunks permuted within each row by
// chunk ^= (row&7). Pure streaming: 1 thread = 32B in / 16B out. Each output
// 64B sector receives a full aligned 4-chunk group (XOR permutes within the
// 128B window) -> sector-complete writes.
// ---------------------------------------------------------------------------
__global__ __launch_bounds__(256)
void hcvt(const float* __restrict__ h, unsigned short* __restrict__ hB) {
    const int g   = blockIdx.x * 256 + threadIdx.x;   // chunk id, 100000*32
    const int row = g >> 5;
    const int c   = g & 31;
    const float4 p0 = *(const float4*)(h + (size_t)row * IN_F + c * 8);
    const float4 p1 = *(const float4*)(h + (size_t)row * IN_F + c * 8 + 4);
    *(bf16x8*)(hB + (size_t)row * IN_F + ((c ^ (row & 7)) * 8)) = cvt_frag(p0, p1);
}

// ---------------------------------------------------------------------------
// Kernel 1: q = fp8(relu(h @ Qw.T + Qb)).  M=100000 N=256(full) K=256.
// Block = 64 rows x 256 cols, 4 waves (wave = 64x64). A staged async from hB
// (bf16, swizzle pre-baked) via global_load_lds — LDS image identical to v7's
// swizzled layout. B-frags direct from global QwB, 2-deep register dbuf.
// Swapped-operand MFMA (verified r8): lane owns row mt*16+fr, dword cols
// nt*4+quad. Epilogue: pack dword -> per-wave LDS quadrant (dword writes,
// XOR (fr&3)<<2 on dword idx) -> uint4 sector-complete stores.
// ---------------------------------------------------------------------------
__global__ __launch_bounds__(256)
void qgemm(const unsigned short* __restrict__ hB, const unsigned short* __restrict__ QwB,
           const float* __restrict__ Qb, unsigned char* __restrict__ q) {
    __shared__ unsigned short ldsA[64 * 256];   // 32 KB; reused as epi tile

    const int tid  = threadIdx.x;
    const int row0 = blockIdx.x * 64;
    const int lane = tid & 63;
    const int wv   = tid >> 6;
    const int wc   = wv << 6;              // wave's 64-col (n) slice
    const int quad = lane >> 4;
    const int fr   = lane & 15;

    // --- Stage A: 8 async 16B copies per thread, linear LDS (chunk g).
    // Per-instr LDS dest = uniform base + lane*16 (g = tid + i*256). Clamped
    // rows (last block) stage donor-row data with mismatched swizzle — their
    // outputs are discarded by the gr<M_TOTAL store guard (garbage in A row m
    // only pollutes output row m).
#pragma unroll
    for (int i = 0; i < 8; ++i) {
        const int g  = tid + i * 256;
        const int gr = min(row0 + (g >> 5), M_TOTAL - 1);
        gload16(hB + (size_t)gr * IN_F + (g & 31) * 8, (char*)ldsA + g * 16);
    }

    // --- B preload (k-step 0) before the barrier: overlaps the stage drain.
    const unsigned short* bp = QwB + (size_t)(wc + fr) * IN_F + quad * 8;
    bf16x8 bvp[2][4];
#pragma unroll
    for (int nt = 0; nt < 4; ++nt)
        bvp[0][nt] = *(const bf16x8*)(bp + nt * 16 * IN_F);

    floatx4 acc[4][4];                     // [nt][mt]
#pragma unroll
    for (int i = 0; i < 4; ++i)
#pragma unroll
        for (int j = 0; j < 4; ++j)
            acc[i][j] = (floatx4){0.f, 0.f, 0.f, 0.f};

    __syncthreads();

#pragma unroll
    for (int kb = 0; kb < 8; ++kb) {       // K=256, 32/step — no barriers
        if (kb < 7) {
#pragma unroll
            for (int nt = 0; nt < 4; ++nt)
                bvp[(kb + 1) & 1][nt] = *(const bf16x8*)(bp + nt * 16 * IN_F + (kb + 1) * 32);
        }
        bf16x8 av[4];
#pragma unroll
        for (int mt = 0; mt < 4; ++mt) {
            const int r = mt * 16 + fr;
            const int c = kb * 4 + quad;
            av[mt] = *(const bf16x8*)(ldsA + r * 256 + ((c ^ (r & 7)) * 8));
        }
#pragma unroll
        for (int nt = 0; nt < 4; ++nt)
#pragma unroll
            for (int mt = 0; mt < 4; ++mt)
                acc[nt][mt] = __builtin_amdgcn_mfma_f32_16x16x32_bf16(bvp[kb & 1][nt], av[mt], acc[nt][mt], 0, 0, 0);
    }

    // --- Epilogue: all waves done reading ldsA; per-wave private 4KB quadrant.
    __syncthreads();
    unsigned* const epi = (unsigned*)ldsA + wv * 1024;   // 64 rows x 16 dwords
#pragma unroll
    for (int nt = 0; nt < 4; ++nt) {
        const float4 b4 = *(const float4*)(Qb + wc + nt * 16 + quad * 4);
#pragma unroll
        for (int mt = 0; mt < 4; ++mt) {
            float v0 = fmaxf(acc[nt][mt][0] + b4.x, 0.f);
            float v1 = fmaxf(acc[nt][mt][1] + b4.y, 0.f);
            float v2 = fmaxf(acc[nt][mt][2] + b4.z, 0.f);
            float v3 = fmaxf(acc[nt][mt][3] + b4.w, 0.f);
            unsigned wpk = (unsigned)__builtin_amdgcn_cvt_pk_fp8_f32(v0, v1, 0, false);
            wpk = (unsigned)__builtin_amdgcn_cvt_pk_fp8_f32(v2, v3, wpk, true);
            // dword D = nt*4+quad of row mt*16+fr, XOR-swizzled on bits 3:2
            epi[(mt * 16 + fr) * 16 + ((((nt ^ (fr & 3)) << 2)) + quad)] = wpk;
        }
    }
    __asm volatile("s_waitcnt lgkmcnt(0)" ::: "memory");   // in-wave write->read

    // Sector-complete stores: 16 rows x 64B per instruction.
#pragma unroll
    for (int i = 0; i < 4; ++i) {
        const int r = i * 16 + (lane >> 2);
        const int s = lane & 3;
        const uint4 val = *(const uint4*)(epi + r * 16 + ((s ^ (r & 3)) << 2));
        const int gr = row0 + r;
        if (gr < M_TOTAL)
            *(uint4*)(q + (size_t)gr * HID_F + wc + s * 16) = val;
    }
}

// ---------------------------------------------------------------------------
// Kernel 2: aggF[n] = sum_t w[n,t]*q[nb[n,t]] / sum_t w[n,t]  (fp32 out).
// One wave/node; 4 neighbors per load instruction (quarter-wave each,
// 16B/lane uint4). 13 iterations (t = 4i + sub, lanes with t>=50 carry w=0).
// ---------------------------------------------------------------------------
__global__ __launch_bounds__(256)
void aggk(const unsigned char* __restrict__ q, const int* __restrict__ nb,
          const float* __restrict__ w, float* __restrict__ aggF) {
    const int node = blockIdx.x * 4 + (threadIdx.x >> 6);
    const int lane = threadIdx.x & 63;

    int   idx_l = 0;
    float w_l   = 0.f;
    if (lane < T_NB) {
        idx_l = nb[(size_t)node * T_NB + lane];
        w_l   = w[(size_t)node * T_NB + lane];
    }
    float sw = w_l;
#pragma unroll
    for (int off = 32; off > 0; off >>= 1)
        sw += __shfl_xor(sw, off, 64);

    const int sub = lane >> 4;       // neighbor slot within group of 4
    const int cg  = lane & 15;       // which 16B column chunk of the row
    float a[16];
#pragma unroll
    for (int j = 0; j < 16; ++j) a[j] = 0.f;

#pragma unroll
    for (int i = 0; i < 13; ++i) {
        const int   t   = 4 * i + sub;              // 0..51; t>=50 has w=0,idx=0
        const int   idx = __shfl(idx_l, t, 64);
        const float wt  = __shfl(w_l, t, 64);
        const uint4 u   = *(const uint4*)(q + (size_t)idx * HID_F + cg * 16);
        v2f p;
        p = __builtin_amdgcn_cvt_pk_f32_fp8(u.x, false); a[0]  += wt * p[0]; a[1]  += wt * p[1];
        p = __builtin_amdgcn_cvt_pk_f32_fp8(u.x, true);  a[2]  += wt * p[0]; a[3]  += wt * p[1];
        p = __builtin_amdgcn_cvt_pk_f32_fp8(u.y, false); a[4]  += wt * p[0]; a[5]  += wt * p[1];
        p = __builtin_amdgcn_cvt_pk_f32_fp8(u.y, true);  a[6]  += wt * p[0]; a[7]  += wt * p[1];
        p = __builtin_amdgcn_cvt_pk_f32_fp8(u.z, false); a[8]  += wt * p[0]; a[9]  += wt * p[1];
        p = __builtin_amdgcn_cvt_pk_f32_fp8(u.z, true);  a[10] += wt * p[0]; a[11] += wt * p[1];
        p = __builtin_amdgcn_cvt_pk_f32_fp8(u.w, false); a[12] += wt * p[0]; a[13] += wt * p[1];
        p = __builtin_amdgcn_cvt_pk_f32_fp8(u.w, true);  a[14] += wt * p[0]; a[15] += wt * p[1];
    }
    // lanes {cg, cg+16, cg+32, cg+48} hold partial sums of the same 16 cols
#pragma unroll
    for (int j = 0; j < 16; ++j) {
        a[j] += __shfl_xor(a[j], 16, 64);
        a[j] += __shfl_xor(a[j], 32, 64);
    }

    if (lane < 16) {
        const float inv = 1.0f / sw;
        float* dst = aggF + (size_t)node * HID_F + cg * 16;
#pragma unroll
        for (int k = 0; k < 4; ++k) {
            float4 o = make_float4(a[4 * k] * inv, a[4 * k + 1] * inv,
                                   a[4 * k + 2] * inv, a[4 * k + 3] * inv);
            *(float4*)(dst + 4 * k) = o;
        }
    }
}

// ---------------------------------------------------------------------------
// Kernel 3: out = relu(concat(h[nodeset], aggF) @ Ww.T + Wb).  M=20000 N=256 K=512.
// 64x128 tile, BK=64, async staging (A gathered fp32, B bf16). Wave = 64x32.
// ---------------------------------------------------------------------------
__global__ __launch_bounds__(256)
void fgemm(const float* __restrict__ h, const int* __restrict__ nodeset,
           const float* __restrict__ aggF, const unsigned short* __restrict__ WwB,
           const float* __restrict__ Wb, float* __restrict__ out) {
    __shared__ char smem[32768];
    float* ldsA = (float*)smem;                              // 64 rows x 16 chunks
    unsigned short* ldsB = (unsigned short*)(smem + 16384);  // 128 rows x 8 chunks

    const int tid  = threadIdx.x;
    const int row0 = blockIdx.x * 64;
    const int n0   = blockIdx.y * 128;
    const int lane = tid & 63;
    const int wv   = tid >> 6;
    const int wc   = wv << 5;
    const int fr   = lane & 15;
    const int fk   = (lane >> 4) << 3;
    const int ca   = fk >> 2;
    const int cbB  = fk >> 3;

    int nsrow[4];
#pragma unroll
    for (int i = 0; i < 4; ++i) {
        const int row = (tid + i * 256) >> 4;
        nsrow[i] = nodeset[min(row0 + row, N_NODES - 1)];
    }

    floatx4 acc[4][2];
#pragma unroll
    for (int i = 0; i < 4; ++i)
#pragma unroll
        for (int j = 0; j < 2; ++j)
            acc[i][j] = (floatx4){0.f, 0.f, 0.f, 0.f};

    for (int kb = 0; kb < 8; ++kb) {
        if (kb) __syncthreads();
#pragma unroll
        for (int i = 0; i < 4; ++i) {
            const int L   = tid + i * 256;
            const int row = L >> 4;
            const int cg  = (L & 15) ^ (row & 15);
            const float* src = (kb < 4)
                ? h    + (size_t)nsrow[i] * IN_F + kb * 64 + cg * 4
                : aggF + (size_t)min(row0 + row, N_NODES - 1) * HID_F + (kb - 4) * 64 + cg * 4;
            gload16(src, smem + L * 16);
        }
#pragma unroll
        for (int i = 0; i < 4; ++i) {
            const int L   = tid + i * 256;
            const int row = L >> 3;
            const int cg  = (L & 7) ^ (row & 7);
            gload16(WwB + (size_t)(n0 + row) * KCAT + kb * 64 + cg * 8, smem + 16384 + L * 16);
        }
        __syncthreads();

#pragma unroll
        for (int ks = 0; ks < 2; ++ks) {
            bf16x8 av[4], bv[2];
#pragma unroll
            for (int mt = 0; mt < 4; ++mt) {
                const int row = mt * 16 + fr;
                const int sw  = row & 15;
                const int c0  = ks * 8 + ca;
                const float4 p0 = *(const float4*)(ldsA + (row * 16 + (c0 ^ sw)) * 4);
                const float4 p1 = *(const float4*)(ldsA + (row * 16 + ((c0 + 1) ^ sw)) * 4);
                av[mt] = cvt_frag(p0, p1);
            }
#pragma unroll
            for (int nt = 0; nt < 2; ++nt) {
                const int row = wc + nt * 16 + fr;
                const int sw  = row & 7;
                bv[nt] = *reinterpret_cast<const bf16x8*>(ldsB + row * 64 + ((ks * 4 + cbB) ^ sw) * 8);
            }
#pragma unroll
            for (int mt = 0; mt < 4; ++mt)
#pragma unroll
                for (int nt = 0; nt < 2; ++nt)
                    acc[mt][nt] = __builtin_amdgcn_mfma_f32_16x16x32_bf16(av[mt], bv[nt], acc[mt][nt], 0, 0, 0);
        }
    }

    const int erow = (lane >> 4) << 2;
    const int ecol = lane & 15;
#pragma unroll
    for (int nt = 0; nt < 2; ++nt) {
        const int gcol = n0 + wc + nt * 16 + ecol;
        const float bias = Wb[gcol];
#pragma unroll
        for (int mt = 0; mt < 4; ++mt)
#pragma unroll
            for (int r = 0; r < 4; ++r) {
                const int gr = row0 + mt * 16 + erow + r;
                if (gr < N_NODES) {
                    const float v = acc[mt][nt][r] + bias;
                    out[(size_t)gr * OUT_F + gcol] = (v > 0.f ? v : 0.f);
                }
            }
    }
}

// ---------------------------------------------------------------------------
// Kernel 4: in-place row L2 normalize. One wave per row.
// ---------------------------------------------------------------------------
__global__ __launch_bounds__(256)
void normk(float* __restrict__ out) {
    const int row = blockIdx.x * 4 + (threadIdx.x >> 6);
    const int lane = threadIdx.x & 63;
    float4 v = *(float4*)(out + (size_t)row * OUT_F + lane * 4);
    float ss = v.x * v.x + v.y * v.y + v.z * v.z + v.w * v.w;
#pragma unroll
    for (int off = 32; off > 0; off >>= 1)
        ss += __shfl_xor(ss, off, 64);
    const float s = rsqrtf(ss);
    v.x *= s; v.y *= s; v.z *= s; v.w *= s;
    *(float4*)(out + (size_t)row * OUT_F + lane * 4) = v;
}

extern "C" void kernel_launch(void* const* d_in, const int* in_sizes, int n_in,
                              void* d_out, int out_size, void* d_ws, size_t ws_size,
                              hipStream_t stream) {
    const float* h        = (const float*)d_in[0];
    const int*   nodeset  = (const int*)d_in[1];
    const int*   nb_nodes = (const int*)d_in[2];
    const float* nb_w     = (const float*)d_in[3];
    const float* Qw       = (const float*)d_in[4];
    const float* Qb       = (const float*)d_in[5];
    const float* Ww       = (const float*)d_in[6];
    const float* Wb       = (const float*)d_in[7];
    float* out = (float*)d_out;

    unsigned char*  q    = (unsigned char*)d_ws;                          // 25.6 MB
    float*          aggF = (float*)((char*)d_ws + 25600000);              // 20.48 MB
    unsigned short* QwB  = (unsigned short*)((char*)d_ws + 46080000);     // 128 KB
    unsigned short* WwB  = (unsigned short*)((char*)d_ws + 46211072);     // 256 KB
    unsigned short* hB   = (unsigned short*)((char*)d_ws + 46473216);     // 51.2 MB

    wcvt <<<dim3(192),                    256, 0, stream>>>(Qw, Ww, QwB, WwB);
    hcvt <<<dim3(12500),                  256, 0, stream>>>(h, hB);
    qgemm<<<dim3((M_TOTAL + 63) / 64),    256, 0, stream>>>(hB, QwB, Qb, q);
    aggk <<<dim3(N_NODES / 4),            256, 0, stream>>>(q, nb_nodes, nb_w, aggF);
    fgemm<<<dim3((N_NODES + 63) / 64, 2), 256, 0, stream>>>(h, nodeset, aggF, WwB, Wb, out);
    normk<<<dim3(N_NODES / 4),            256, 0, stream>>>(out);
}

// Round 4
// 254.815 us; speedup vs baseline: 1.0615x; 1.0615x over previous
//
#include <hip/hip_runtime.h>
#include <hip/hip_bf16.h>

// PinSageConv on MI355X — round 11.
// qgemm v11: de-hcvt. r3 split conversion into a standalone hB pass (+24 µs
// streaming) that exactly ate qgemm's async-staging gain (~-20 µs) -> net 0.
// v11 reads h (f32) directly and converts in-register, but with the stage
// split into an explicit batch-load phase (16 independent float4 = 64 VGPR
// in flight -> 2x v8's MLP) and a separate cvt/ds_write phase; B k0-preload
// issues between the two so it rides the same memory window. Keeps the
// r2/r3-verified swapped-operand MFMA core (lane owns row mt*16+fr, dword
// cols nt*4+quad), the r3 dword-XOR LDS epilogue and sector-complete uint4
// stores. aggk/fgemm/normk unchanged.
// Workspace: q_fp8[100000][256] @0 (25.6MB) | aggF[20000][256] f32 @25.6MB
//            | QwB bf16 @46,080,000 | WwB bf16 @46,211,072.

#define M_TOTAL 100000
#define N_NODES 20000
#define T_NB    50
#define IN_F    256
#define HID_F   256
#define OUT_F   256
#define KCAT    512

typedef __bf16 bf16x8 __attribute__((ext_vector_type(8)));
typedef float  floatx4 __attribute__((ext_vector_type(4)));
typedef float  v2f     __attribute__((ext_vector_type(2)));

__device__ __forceinline__ unsigned short f2bf(float f) {
    unsigned int u = __float_as_uint(f);
    u += 0x7fffu + ((u >> 16) & 1u);          // RTNE
    return (unsigned short)(u >> 16);
}
__device__ __forceinline__ void gload16(const void* g, void* l) {
    __builtin_amdgcn_global_load_lds(
        (const __attribute__((address_space(1))) unsigned int*)g,
        (__attribute__((address_space(3))) unsigned int*)l, 16, 0, 0);
}
__device__ __forceinline__ bf16x8 cvt_frag(float4 a, float4 b) {
    bf16x8 r;
    r[0] = (__bf16)a.x; r[1] = (__bf16)a.y; r[2] = (__bf16)a.z; r[3] = (__bf16)a.w;
    r[4] = (__bf16)b.x; r[5] = (__bf16)b.y; r[6] = (__bf16)b.z; r[7] = (__bf16)b.w;
    return r;
}

// ---------------------------------------------------------------------------
// Kernel 0: convert Qw (65536 f32) and Ww (131072 f32) to bf16.
// ---------------------------------------------------------------------------
__global__ __launch_bounds__(256)
void wcvt(const float* __restrict__ Qw, const float* __restrict__ Ww,
          unsigned short* __restrict__ QwB, unsigned short* __restrict__ WwB) {
    const int e = (blockIdx.x * 256 + threadIdx.x) * 4;
    float4 v;
    unsigned short* dst;
    if (e < 65536) { v = *(const float4*)(Qw + e);           dst = QwB + e; }
    else           { v = *(const float4*)(Ww + (e - 65536)); dst = WwB + (e - 65536); }
    ushort4 s;
    s.x = f2bf(v.x); s.y = f2bf(v.y); s.z = f2bf(v.z); s.w = f2bf(v.w);
    *(ushort4*)dst = s;
}

// ---------------------------------------------------------------------------
// Kernel 1: q = fp8(relu(h @ Qw.T + Qb)).  M=100000 N=256(full) K=256.
// Block = 64 rows x 256 cols, 4 waves (wave = 64x64). A staged from h (f32):
// batch-load 16 float4 -> cvt -> swizzled bf16 LDS (chunk ^= row&7).
// B-frags direct from global QwB (L2-hot), 2-deep register dbuf, k0 preload
// issued inside the stage-load window. Swapped-operand MFMA; epilogue packs
// fp8 dwords into a per-wave LDS quadrant (XOR on dword idx) then stores
// sector-complete uint4.
// ---------------------------------------------------------------------------
__global__ __launch_bounds__(256)
void qgemm(const float* __restrict__ h, const unsigned short* __restrict__ QwB,
           const float* __restrict__ Qb, unsigned char* __restrict__ q) {
    __shared__ unsigned short ldsA[64 * 256];   // 32 KB; reused as epi tile

    const int tid  = threadIdx.x;
    const int row0 = blockIdx.x * 64;
    const int lane = tid & 63;
    const int wv   = tid >> 6;
    const int wc   = wv << 6;              // wave's 64-col (n) slice
    const int quad = lane >> 4;
    const int fr   = lane & 15;

    // --- Stage A phase 1: 16 independent float4 loads (64 VGPR in flight).
    float4 pa[8], pb[8];
#pragma unroll
    for (int i = 0; i < 8; ++i) {
        const int C  = tid + i * 256;
        const int gr = min(row0 + (C >> 5), M_TOTAL - 1);
        const float* src = h + (size_t)gr * IN_F + (C & 31) * 8;
        pa[i] = *(const float4*)src;
        pb[i] = *(const float4*)(src + 4);
    }

    // --- B k0 preload issues while the h loads are in flight.
    const unsigned short* bp = QwB + (size_t)(wc + fr) * IN_F + quad * 8;
    bf16x8 bvp[2][4];
#pragma unroll
    for (int nt = 0; nt < 4; ++nt)
        bvp[0][nt] = *(const bf16x8*)(bp + nt * 16 * IN_F);

    // --- Stage A phase 2: convert + swizzled LDS write (chunk c ^= row&7).
#pragma unroll
    for (int i = 0; i < 8; ++i) {
        const int C = tid + i * 256;
        const int r = C >> 5;
        const int c = C & 31;
        *(bf16x8*)(ldsA + r * 256 + ((c ^ (r & 7)) * 8)) = cvt_frag(pa[i], pb[i]);
    }

    floatx4 acc[4][4];                     // [nt][mt]
#pragma unroll
    for (int i = 0; i < 4; ++i)
#pragma unroll
        for (int j = 0; j < 4; ++j)
            acc[i][j] = (floatx4){0.f, 0.f, 0.f, 0.f};

    __syncthreads();

#pragma unroll
    for (int kb = 0; kb < 8; ++kb) {       // K=256, 32/step — no barriers
        if (kb < 7) {
#pragma unroll
            for (int nt = 0; nt < 4; ++nt)
                bvp[(kb + 1) & 1][nt] = *(const bf16x8*)(bp + nt * 16 * IN_F + (kb + 1) * 32);
        }
        bf16x8 av[4];
#pragma unroll
        for (int mt = 0; mt < 4; ++mt) {
            const int r = mt * 16 + fr;
            const int c = kb * 4 + quad;
            av[mt] = *(const bf16x8*)(ldsA + r * 256 + ((c ^ (r & 7)) * 8));
        }
#pragma unroll
        for (int nt = 0; nt < 4; ++nt)
#pragma unroll
            for (int mt = 0; mt < 4; ++mt)
                acc[nt][mt] = __builtin_amdgcn_mfma_f32_16x16x32_bf16(bvp[kb & 1][nt], av[mt], acc[nt][mt], 0, 0, 0);
    }

    // --- Epilogue: all waves done reading ldsA; per-wave private 4KB quadrant.
    __syncthreads();
    unsigned* const epi = (unsigned*)ldsA + wv * 1024;   // 64 rows x 16 dwords
#pragma unroll
    for (int nt = 0; nt < 4; ++nt) {
        const float4 b4 = *(const float4*)(Qb + wc + nt * 16 + quad * 4);
#pragma unroll
        for (int mt = 0; mt < 4; ++mt) {
            float v0 = fmaxf(acc[nt][mt][0] + b4.x, 0.f);
            float v1 = fmaxf(acc[nt][mt][1] + b4.y, 0.f);
            float v2 = fmaxf(acc[nt][mt][2] + b4.z, 0.f);
            float v3 = fmaxf(acc[nt][mt][3] + b4.w, 0.f);
            unsigned wpk = (unsigned)__builtin_amdgcn_cvt_pk_fp8_f32(v0, v1, 0, false);
            wpk = (unsigned)__builtin_amdgcn_cvt_pk_fp8_f32(v2, v3, wpk, true);
            // dword D = nt*4+quad of row mt*16+fr, XOR-swizzled on bits 3:2
            epi[(mt * 16 + fr) * 16 + ((((nt ^ (fr & 3)) << 2)) + quad)] = wpk;
        }
    }
    __asm volatile("s_waitcnt lgkmcnt(0)" ::: "memory");   // in-wave write->read

    // Sector-complete stores: 16 rows x 64B per instruction.
#pragma unroll
    for (int i = 0; i < 4; ++i) {
        const int r = i * 16 + (lane >> 2);
        const int s = lane & 3;
        const uint4 val = *(const uint4*)(epi + r * 16 + ((s ^ (r & 3)) << 2));
        const int gr = row0 + r;
        if (gr < M_TOTAL)
            *(uint4*)(q + (size_t)gr * HID_F + wc + s * 16) = val;
    }
}

// ---------------------------------------------------------------------------
// Kernel 2: aggF[n] = sum_t w[n,t]*q[nb[n,t]] / sum_t w[n,t]  (fp32 out).
// One wave/node; 4 neighbors per load instruction (quarter-wave each,
// 16B/lane uint4). 13 iterations (t = 4i + sub, lanes with t>=50 carry w=0).
// ---------------------------------------------------------------------------
__global__ __launch_bounds__(256)
void aggk(const unsigned char* __restrict__ q, const int* __restrict__ nb,
          const float* __restrict__ w, float* __restrict__ aggF) {
    const int node = blockIdx.x * 4 + (threadIdx.x >> 6);
    const int lane = threadIdx.x & 63;

    int   idx_l = 0;
    float w_l   = 0.f;
    if (lane < T_NB) {
        idx_l = nb[(size_t)node * T_NB + lane];
        w_l   = w[(size_t)node * T_NB + lane];
    }
    float sw = w_l;
#pragma unroll
    for (int off = 32; off > 0; off >>= 1)
        sw += __shfl_xor(sw, off, 64);

    const int sub = lane >> 4;       // neighbor slot within group of 4
    const int cg  = lane & 15;       // which 16B column chunk of the row
    float a[16];
#pragma unroll
    for (int j = 0; j < 16; ++j) a[j] = 0.f;

#pragma unroll
    for (int i = 0; i < 13; ++i) {
        const int   t   = 4 * i + sub;              // 0..51; t>=50 has w=0,idx=0
        const int   idx = __shfl(idx_l, t, 64);
        const float wt  = __shfl(w_l, t, 64);
        const uint4 u   = *(const uint4*)(q + (size_t)idx * HID_F + cg * 16);
        v2f p;
        p = __builtin_amdgcn_cvt_pk_f32_fp8(u.x, false); a[0]  += wt * p[0]; a[1]  += wt * p[1];
        p = __builtin_amdgcn_cvt_pk_f32_fp8(u.x, true);  a[2]  += wt * p[0]; a[3]  += wt * p[1];
        p = __builtin_amdgcn_cvt_pk_f32_fp8(u.y, false); a[4]  += wt * p[0]; a[5]  += wt * p[1];
        p = __builtin_amdgcn_cvt_pk_f32_fp8(u.y, true);  a[6]  += wt * p[0]; a[7]  += wt * p[1];
        p = __builtin_amdgcn_cvt_pk_f32_fp8(u.z, false); a[8]  += wt * p[0]; a[9]  += wt * p[1];
        p = __builtin_amdgcn_cvt_pk_f32_fp8(u.z, true);  a[10] += wt * p[0]; a[11] += wt * p[1];
        p = __builtin_amdgcn_cvt_pk_f32_fp8(u.w, false); a[12] += wt * p[0]; a[13] += wt * p[1];
        p = __builtin_amdgcn_cvt_pk_f32_fp8(u.w, true);  a[14] += wt * p[0]; a[15] += wt * p[1];
    }
    // lanes {cg, cg+16, cg+32, cg+48} hold partial sums of the same 16 cols
#pragma unroll
    for (int j = 0; j < 16; ++j) {
        a[j] += __shfl_xor(a[j], 16, 64);
        a[j] += __shfl_xor(a[j], 32, 64);
    }

    if (lane < 16) {
        const float inv = 1.0f / sw;
        float* dst = aggF + (size_t)node * HID_F + cg * 16;
#pragma unroll
        for (int k = 0; k < 4; ++k) {
            float4 o = make_float4(a[4 * k] * inv, a[4 * k + 1] * inv,
                                   a[4 * k + 2] * inv, a[4 * k + 3] * inv);
            *(float4*)(dst + 4 * k) = o;
        }
    }
}

// ---------------------------------------------------------------------------
// Kernel 3: out = relu(concat(h[nodeset], aggF) @ Ww.T + Wb).  M=20000 N=256 K=512.
// 64x128 tile, BK=64, async staging (A gathered fp32, B bf16). Wave = 64x32.
// ---------------------------------------------------------------------------
__global__ __launch_bounds__(256)
void fgemm(const float* __restrict__ h, const int* __restrict__ nodeset,
           const float* __restrict__ aggF, const unsigned short* __restrict__ WwB,
           const float* __restrict__ Wb, float* __restrict__ out) {
    __shared__ char smem[32768];
    float* ldsA = (float*)smem;                              // 64 rows x 16 chunks
    unsigned short* ldsB = (unsigned short*)(smem + 16384);  // 128 rows x 8 chunks

    const int tid  = threadIdx.x;
    const int row0 = blockIdx.x * 64;
    const int n0   = blockIdx.y * 128;
    const int lane = tid & 63;
    const int wv   = tid >> 6;
    const int wc   = wv << 5;
    const int fr   = lane & 15;
    const int fk   = (lane >> 4) << 3;
    const int ca   = fk >> 2;
    const int cbB  = fk >> 3;

    int nsrow[4];
#pragma unroll
    for (int i = 0; i < 4; ++i) {
        const int row = (tid + i * 256) >> 4;
        nsrow[i] = nodeset[min(row0 + row, N_NODES - 1)];
    }

    floatx4 acc[4][2];
#pragma unroll
    for (int i = 0; i < 4; ++i)
#pragma unroll
        for (int j = 0; j < 2; ++j)
            acc[i][j] = (floatx4){0.f, 0.f, 0.f, 0.f};

    for (int kb = 0; kb < 8; ++kb) {
        if (kb) __syncthreads();
#pragma unroll
        for (int i = 0; i < 4; ++i) {
            const int L   = tid + i * 256;
            const int row = L >> 4;
            const int cg  = (L & 15) ^ (row & 15);
            const float* src = (kb < 4)
                ? h    + (size_t)nsrow[i] * IN_F + kb * 64 + cg * 4
                : aggF + (size_t)min(row0 + row, N_NODES - 1) * HID_F + (kb - 4) * 64 + cg * 4;
            gload16(src, smem + L * 16);
        }
#pragma unroll
        for (int i = 0; i < 4; ++i) {
            const int L   = tid + i * 256;
            const int row = L >> 3;
            const int cg  = (L & 7) ^ (row & 7);
            gload16(WwB + (size_t)(n0 + row) * KCAT + kb * 64 + cg * 8, smem + 16384 + L * 16);
        }
        __syncthreads();

#pragma unroll
        for (int ks = 0; ks < 2; ++ks) {
            bf16x8 av[4], bv[2];
#pragma unroll
            for (int mt = 0; mt < 4; ++mt) {
                const int row = mt * 16 + fr;
                const int sw  = row & 15;
                const int c0  = ks * 8 + ca;
                const float4 p0 = *(const float4*)(ldsA + (row * 16 + (c0 ^ sw)) * 4);
                const float4 p1 = *(const float4*)(ldsA + (row * 16 + ((c0 + 1) ^ sw)) * 4);
                av[mt] = cvt_frag(p0, p1);
            }
#pragma unroll
            for (int nt = 0; nt < 2; ++nt) {
                const int row = wc + nt * 16 + fr;
                const int sw  = row & 7;
                bv[nt] = *reinterpret_cast<const bf16x8*>(ldsB + row * 64 + ((ks * 4 + cbB) ^ sw) * 8);
            }
#pragma unroll
            for (int mt = 0; mt < 4; ++mt)
#pragma unroll
                for (int nt = 0; nt < 2; ++nt)
                    acc[mt][nt] = __builtin_amdgcn_mfma_f32_16x16x32_bf16(av[mt], bv[nt], acc[mt][nt], 0, 0, 0);
        }
    }

    const int erow = (lane >> 4) << 2;
    const int ecol = lane & 15;
#pragma unroll
    for (int nt = 0; nt < 2; ++nt) {
        const int gcol = n0 + wc + nt * 16 + ecol;
        const float bias = Wb[gcol];
#pragma unroll
        for (int mt = 0; mt < 4; ++mt)
#pragma unroll
            for (int r = 0; r < 4; ++r) {
                const int gr = row0 + mt * 16 + erow + r;
                if (gr < N_NODES) {
                    const float v = acc[mt][nt][r] + bias;
                    out[(size_t)gr * OUT_F + gcol] = (v > 0.f ? v : 0.f);
                }
            }
    }
}

// ---------------------------------------------------------------------------
// Kernel 4: in-place row L2 normalize. One wave per row.
// ---------------------------------------------------------------------------
__global__ __launch_bounds__(256)
void normk(float* __restrict__ out) {
    const int row = blockIdx.x * 4 + (threadIdx.x >> 6);
    const int lane = threadIdx.x & 63;
    float4 v = *(float4*)(out + (size_t)row * OUT_F + lane * 4);
    float ss = v.x * v.x + v.y * v.y + v.z * v.z + v.w * v.w;
#pragma unroll
    for (int off = 32; off > 0; off >>= 1)
        ss += __shfl_xor(ss, off, 64);
    const float s = rsqrtf(ss);
    v.x *= s; v.y *= s; v.z *= s; v.w *= s;
    *(float4*)(out + (size_t)row * OUT_F + lane * 4) = v;
}

extern "C" void kernel_launch(void* const* d_in, const int* in_sizes, int n_in,
                              void* d_out, int out_size, void* d_ws, size_t ws_size,
                              hipStream_t stream) {
    const float* h        = (const float*)d_in[0];
    const int*   nodeset  = (const int*)d_in[1];
    const int*   nb_nodes = (const int*)d_in[2];
    const float* nb_w     = (const float*)d_in[3];
    const float* Qw       = (const float*)d_in[4];
    const float* Qb       = (const float*)d_in[5];
    const float* Ww       = (const float*)d_in[6];
    const float* Wb       = (const float*)d_in[7];
    float* out = (float*)d_out;

    unsigned char*  q    = (unsigned char*)d_ws;                          // 25.6 MB
    float*          aggF = (float*)((char*)d_ws + 25600000);              // 20.48 MB
    unsigned short* QwB  = (unsigned short*)((char*)d_ws + 46080000);     // 128 KB
    unsigned short* WwB  = (unsigned short*)((char*)d_ws + 46211072);     // 256 KB

    wcvt <<<dim3(192),                    256, 0, stream>>>(Qw, Ww, QwB, WwB);
    qgemm<<<dim3((M_TOTAL + 63) / 64),    256, 0, stream>>>(h, QwB, Qb, q);
    aggk <<<dim3(N_NODES / 4),            256, 0, stream>>>(q, nb_nodes, nb_w, aggF);
    fgemm<<<dim3((N_NODES + 63) / 64, 2), 256, 0, stream>>>(h, nodeset, aggF, WwB, Wb, out);
    normk<<<dim3(N_NODES / 4),            256, 0, stream>>>(out);
}